// Round 12
// baseline (2251.172 us; speedup 1.0000x reference)
//
#include <hip/hip_runtime.h>

#define BATCH 16
#define CH    64
#define LEN   4096
#define NCODE 1024
#define NPTS  (BATCH * LEN)          // 65536
#define MT    128                    // points per block (2 per lane)
#define NW    8                      // waves per block = code slices
#define CPW   (NCODE / NW)           // 128 codes per wave
#define CG    16                     // codes per group (one s_load_dwordx16)
#define NGRP  (CPW / CG)             // 8 groups
#define NPART (NPTS / MT)            // 512 partials

typedef float float2v __attribute__((ext_vector_type(2)));
typedef float float4v __attribute__((ext_vector_type(4)));

// ---------------------------------------------------------------------------
// Kernel 1 (prep): cbt[c][k] = cb[k][c]  and  w2[k] = sum_c cb[k][c]^2.
// ---------------------------------------------------------------------------
__global__ __launch_bounds__(256) void vq_prep(const float* __restrict__ cb,
                                               float* __restrict__ cbt,
                                               float* __restrict__ w2) {
    __shared__ float tile[64][65];
    const int k0 = blockIdx.x * 64;
    const int t  = threadIdx.x;
#pragma unroll
    for (int r = 0; r < 16; ++r) {
        int idx = r * 256 + t;            // over 64 codes x 64 ch
        int k = idx >> 6, c = idx & 63;
        tile[k][c] = cb[(size_t)(k0 + k) * CH + c];
    }
    __syncthreads();
#pragma unroll
    for (int r = 0; r < 16; ++r) {
        int idx = r * 256 + t;
        int c = idx >> 6, k = idx & 63;   // write coalesced in k
        cbt[(size_t)c * NCODE + k0 + k] = tile[k][c];
    }
    if (t < 64) {
        float s = 0.f;
#pragma unroll
        for (int c = 0; c < CH; ++c) s = fmaf(tile[t][c], tile[t][c], s);
        w2[k0 + t] = s;
    }
}

// ---------------------------------------------------------------------------
// Kernel 2: argmin — LDS-x / scalar-codebook hybrid.
// 512 thr = 8 waves; wave = one 128-code slice; lane owns 2 points.
// x staged ONCE in LDS (r11's global-x re-reads missed L1/L2 -> 2.87GB HBM).
// Per c-step: 1 ds_read_b64 (conflict-free, 0.25 B/MAC -> far below the
// 69 TB/s LDS wall that capped r7/r10 at ~125us) + 1 wave-uniform
// s_load_dwordx16 + 32 v_fmac v,s,v. acc[2][16] static -> RA-safe.
// Merge arrays overlaid on xs after a barrier: LDS 33KB -> 4 blocks/CU.
// ---------------------------------------------------------------------------
__global__ __launch_bounds__(512, 4) void vq_argmin(const float*  __restrict__ x,
                                                    const float*  __restrict__ cbt,
                                                    const float*  __restrict__ w2,
                                                    float*        __restrict__ idx_out,
                                                    double*       __restrict__ partial) {
    __shared__ __attribute__((aligned(16))) float xs[CH * MT];   // 32KB, overlaid later

    const int t    = threadIdx.x;
    const int lane = t & 63;
    const int wv   = __builtin_amdgcn_readfirstlane(t >> 6);   // 0..7, scalar
    const int p0   = blockIdx.x * MT;
    const int b    = p0 >> 12;          // / LEN
    const int l0   = p0 & (LEN - 1);

    // ---- stage x tile: xs[c][l] = x[b][c][l0+l]  (coalesced float4)
#pragma unroll
    for (int r = 0; r < 4; ++r) {
        int idx = r * 512 + t;          // 2048 float4s
        int c   = idx >> 5;             // 32 float4 per row
        int l4  = idx & 31;
        *(float4v*)&xs[c * MT + 4 * l4] =
            *(const float4v*)&x[((size_t)b * CH + c) * LEN + l0 + 4 * l4];
    }
    __syncthreads();

    // ---- |x|^2 for my 2 points
    float x2a = 0.f, x2b = 0.f;
#pragma unroll
    for (int c = 0; c < CH; ++c) {
        float2v v = *(const float2v*)&xs[c * MT + 2 * lane];
        x2a = fmaf(v.x, v.x, x2a);
        x2b = fmaf(v.y, v.y, x2b);
    }

    const float* __restrict__ wp  = cbt + wv * CPW;   // scalar base, cbt[c][k]
    const float* __restrict__ w2p = w2 + wv * CPW;    // scalar base

    float best0 = 3.4e38f, best1 = 3.4e38f;
    int   bk0 = 0, bk1 = 0;

    for (int g = 0; g < NGRP; ++g) {
        float acc0[CG], acc1[CG];
#pragma unroll
        for (int j = 0; j < CG; ++j) { acc0[j] = 0.f; acc1[j] = 0.f; }

#pragma unroll
        for (int c = 0; c < CH; ++c) {
            float2v xa = *(const float2v*)&xs[c * MT + 2 * lane];  // ds_read_b64
            const float* wr = wp + (size_t)c * NCODE + g * CG;     // s_load_dwordx16
#pragma unroll
            for (int j = 0; j < CG; ++j) {
                acc0[j] = fmaf(xa.x, wr[j], acc0[j]);   // v_fmac v,s,v
                acc1[j] = fmaf(xa.y, wr[j], acc1[j]);
            }
        }

        // cost = w2[k] - 2*dot (x2 constant per point -> same argmin; strict <
        // ascending k = first-occurrence, identical to r11's passing scheme)
#pragma unroll
        for (int j = 0; j < CG; ++j) {
            int   k   = g * CG + j;
            float w2k = w2p[k];
            float c0  = fmaf(-2.0f, acc0[j], w2k);
            float c1  = fmaf(-2.0f, acc1[j], w2k);
            if (c0 < best0) { best0 = c0; bk0 = k; }
            if (c1 < best1) { best1 = c1; bk1 = k; }
        }
    }
    bk0 += wv * CPW;
    bk1 += wv * CPW;

    // ---- overlay merge arrays onto xs (all xs reads are complete)
    __syncthreads();
    float*  sb0  = xs;                      // [NW*64]
    int*    sk0  = (int*)(xs + 512);        // [NW*64]
    float*  sb1  = xs + 1024;               // [NW*64]
    int*    sk1  = (int*)(xs + 1536);       // [NW*64]
    double* ssum = (double*)(xs + 2048);    // [64]

    sb0[wv * 64 + lane] = best0;  sk0[wv * 64 + lane] = bk0;
    sb1[wv * 64 + lane] = best1;  sk1[wv * 64 + lane] = bk1;
    __syncthreads();

    if (wv == 0) {
        // merge slices in ascending order (strict < keeps lowest k on ties)
#pragma unroll
        for (int s = 1; s < NW; ++s) {
            float ob0 = sb0[s * 64 + lane];
            int   ok0 = sk0[s * 64 + lane];
            if (ob0 < best0) { best0 = ob0; bk0 = ok0; }
            float ob1 = sb1[s * 64 + lane];
            int   ok1 = sk1[s * 64 + lane];
            if (ob1 < best1) { best1 = ob1; bk1 = ok1; }
        }
        float2v iv; iv.x = (float)bk0; iv.y = (float)bk1;
        *(float2v*)(idx_out + p0 + 2 * lane) = iv;
        // min d2 = x2 + (w2 - 2*dot)
        ssum[lane] = ((double)x2a + (double)best0) + ((double)x2b + (double)best1);
    }
    __syncthreads();

    if (t == 0) {
        double s = 0.0;
        for (int i = 0; i < 64; ++i) s += ssum[i];
        partial[blockIdx.x] = s;
    }
}

// ---------------------------------------------------------------------------
// Kernel 3: quant_out[b,c,l] = codebook[idx[b,l], c]  (coalesced writes)
// ---------------------------------------------------------------------------
__global__ __launch_bounds__(256) void vq_gather(const float* __restrict__ cbk,
                                                 const float* __restrict__ idx_f,
                                                 float*       __restrict__ out) {
    int t  = blockIdx.x * 256 + threadIdx.x;   // over B*C*L
    int l  = t & (LEN - 1);
    int bc = t >> 12;
    int c  = bc & (CH - 1);
    int b  = bc >> 6;
    int k  = (int)idx_f[b * LEN + l];
    out[t] = cbk[(size_t)k * CH + c];
}

// ---------------------------------------------------------------------------
// Kernel 4: final loss reduction over the NPART per-block partials.
// ---------------------------------------------------------------------------
__global__ __launch_bounds__(256) void vq_loss(const double* __restrict__ partial,
                                               float*        __restrict__ losses) {
    __shared__ double sred[256];
    double v = 0.0;
#pragma unroll
    for (int i = 0; i < NPART / 256; ++i) v += partial[threadIdx.x + 256 * i];
    sred[threadIdx.x] = v;
    __syncthreads();
    for (int s = 128; s > 0; s >>= 1) {
        if (threadIdx.x < s) sred[threadIdx.x] += sred[threadIdx.x + s];
        __syncthreads();
    }
    if (threadIdx.x == 0) {
        float loss = (float)(sred[0] / (double)((size_t)NPTS * CH));
        losses[0] = loss;   // codebook_loss
        losses[1] = loss;   // commitment_loss (same value)
    }
}

// ---------------------------------------------------------------------------
extern "C" void kernel_launch(void* const* d_in, const int* in_sizes, int n_in,
                              void* d_out, int out_size, void* d_ws, size_t ws_size,
                              hipStream_t stream) {
    const float* x  = (const float*)d_in[0];   // (B, C, L)
    const float* cb = (const float*)d_in[1];   // (K, C)
    float* out = (float*)d_out;

    // d_out layout: [quant_out (B*C*L)] [codebook_loss] [commitment_loss] [indices (B*L)]
    float* quant_out = out;
    float* losses    = out + (size_t)BATCH * CH * LEN;
    float* idx_out   = losses + 2;

    // ws: [0,8KB) double partials; [8KB,12KB) w2; [16KB,16KB+256KB) cbt
    double* partial = (double*)d_ws;
    float*  w2      = (float*)((char*)d_ws + 8192);
    float*  cbt     = (float*)((char*)d_ws + 16384);

    vq_prep<<<NCODE / 64, 256, 0, stream>>>(cb, cbt, w2);
    vq_argmin<<<NPTS / MT, 512, 0, stream>>>(x, cbt, w2, idx_out, partial);
    vq_gather<<<(BATCH * CH * LEN) / 256, 256, 0, stream>>>(cb, idx_out, quant_out);
    vq_loss<<<1, 256, 0, stream>>>(partial, losses);
}